// Round 12
// baseline (56882.916 us; speedup 1.0000x reference)
//
#include <hip/hip_runtime.h>
#include <hip/hip_bf16.h>
#include <math.h>

// ---------------- problem constants ----------------
constexpr int NB  = 8;
constexpr int TT  = 4096;
constexpr int DD  = 256;
constexpr int CK  = 64;
constexpr int NCK = 64;
constexpr float ETA_SC = 1e-3f;
constexpr float EPSV   = 1e-6f;

constexpr size_t MSZ = (size_t)DD*DD;   // 65536

// ---------- fp32 region (element offsets into float* W) ----------
constexpr size_t OFF_W2  = 0;                               // [8][6][256*256]
constexpr size_t OFF_W1B = OFF_W2  + (size_t)NB*6*MSZ;      // [8][4][256*256]  (k,v,q,mem)
constexpr size_t OFF_W1S = OFF_W1B + (size_t)NB*4*MSZ;      // [8][2][256]
constexpr size_t OFF_WSK = OFF_W1S + (size_t)NB*2*DD;       // [8][2][256]
constexpr size_t OFF_SCK = OFF_WSK + (size_t)NB*2*DD;       // [8][64]
constexpr size_t OFF_SCQ = OFF_SCK + (size_t)NB*CK;         // [8][64]
constexpr size_t OFF_VSUM= OFF_SCQ + (size_t)NB*CK;         // [8][64]
constexpr size_t OFF_ETA = OFF_VSUM+ (size_t)NB*CK;         // [8][64]
constexpr size_t OFF_GS  = OFF_ETA + (size_t)NB*CK;         // [8][2][64]
constexpr size_t OFF_ABAR= OFF_GS  + (size_t)NB*2*CK;       // [8]
constexpr size_t FTOT    = OFF_ABAR + NB;

// ---------- bf16 region (element offsets into __hip_bfloat16* B) ----------
constexpr size_t BOFF_HX = 0;                               // [8][5][64][256]
constexpr size_t BOFF_F  = BOFF_HX + (size_t)NB*5*CK*DD;    // [3][8][64][256]
constexpr size_t BOFF_ZU = BOFF_F  + (size_t)3*NB*CK*DD;    // [8][6][64][256]
constexpr size_t BOFF_ZO = BOFF_ZU + (size_t)NB*6*CK*DD;    // [8][64][256]
constexpr size_t BOFF_GB = BOFF_ZO + (size_t)NB*CK*DD;      // [8][4][64][256]
constexpr size_t BOFF_P  = BOFF_GB + (size_t)NB*4*CK*DD;    // [8][6][64][256]

__device__ __forceinline__ int bigIdx(int m){ return (m==5)?3:m; }

__device__ __forceinline__ float geluf(float z){
  return 0.5f*z*(1.0f + erff(z*0.70710678118654752440f));
}
__device__ __forceinline__ float dgeluf(float z){
  float cdf = 0.5f*(1.0f + erff(z*0.70710678118654752440f));
  float pdf = expf(-0.5f*z*z)*0.39894228040143267794f;
  return cdf + z*pdf;
}
__device__ __forceinline__ float bf(__hip_bfloat16 v){ return __bfloat162float(v); }
__device__ __forceinline__ float wsum(float v){
  #pragma unroll
  for (int off=32; off>0; off>>=1) v += __shfl_xor(v, off, 64);
  return v;
}

// ---------------- init ----------------
__global__ __launch_bounds__(256) void initk(float* __restrict__ W,
  const float* kw1, const float* kw2, const float* vw1, const float* vw2,
  const float* qw1, const float* qw2, const float* ew1, const float* ew2,
  const float* ewsk, const float* aw1, const float* aw2, const float* awsk,
  const float* mw1, const float* mw2)
{
  int b = blockIdx.x/6, m = blockIdx.x%6;
  const float *w1s=nullptr,*w2s=nullptr,*wsks=nullptr;
  switch(m){
    case 0: w1s=kw1; w2s=kw2; break;
    case 1: w1s=vw1; w2s=vw2; break;
    case 2: w1s=qw1; w2s=qw2; break;
    case 3: w1s=ew1; w2s=ew2; wsks=ewsk; break;
    case 4: w1s=aw1; w2s=aw2; wsks=awsk; break;
    default: w1s=mw1; w2s=mw2; break;
  }
  float* w2d = W + OFF_W2 + ((size_t)b*6+m)*MSZ;
  for (size_t i=threadIdx.x; i<MSZ; i+=256) w2d[i] = w2s[i];
  if (m==3 || m==4){
    int sm = m-3;
    float* w1d = W + OFF_W1S + ((size_t)b*2+sm)*DD;
    float* wsd = W + OFF_WSK + ((size_t)b*2+sm)*DD;
    for (int i=threadIdx.x;i<DD;i+=256){ w1d[i]=w1s[i]; wsd[i]=wsks[i]; }
  } else {
    float* w1d = W + OFF_W1B + ((size_t)b*4+bigIdx(m))*MSZ;
    for (size_t i=threadIdx.x;i<MSZ;i+=256) w1d[i] = w1s[i];
  }
}

// ---------------- k1: Hx = gelu(x @ w2^T) for mems 0..4  (grid NB*5) ----------------
__global__ __launch_bounds__(256) void k1(const float* __restrict__ x,
        const float* __restrict__ W, __hip_bfloat16* __restrict__ B, int chunk)
{
  int b = blockIdx.x/5, m = blockIdx.x%5, c = threadIdx.x;
  __shared__ __align__(16) float sT[64*68];
  const float* w2 = W + OFF_W2 + ((size_t)b*6+m)*MSZ;
  const float* xp = x + ((size_t)b*TT + (size_t)chunk*CK)*DD;
  float zz[64];
  #pragma unroll
  for (int t=0;t<64;t++) zz[t]=0.0f;
  for (int seg=0; seg<4; seg++){
    int i0 = seg*64;
    for (int l=threadIdx.x; l<4096; l+=256){
      int t=l>>6, ii=l&63;
      sT[t*68+ii] = xp[(size_t)t*DD + i0+ii];
    }
    __syncthreads();
    for (int j=0;j<16;j++){
      float4 wv = *(const float4*)(w2 + (size_t)c*DD + i0 + j*4);
      #pragma unroll
      for (int t=0;t<64;t++){
        float4 xv = *(const float4*)(sT + t*68 + j*4);
        zz[t] += xv.x*wv.x + xv.y*wv.y + xv.z*wv.z + xv.w*wv.w;
      }
    }
    __syncthreads();
  }
  __hip_bfloat16* hx = B + BOFF_HX + ((size_t)(b*5+m)*CK)*DD;
  #pragma unroll
  for (int t=0;t<64;t++) hx[(size_t)t*DD+c] = __float2bfloat16(geluf(zz[t]));
}

// ---------------- k2: F = x + Hx @ w1^T for mems 0..2  (grid NB*3) ----------------
__global__ __launch_bounds__(256) void k2(const float* __restrict__ x,
        const float* __restrict__ W, __hip_bfloat16* __restrict__ B, int chunk)
{
  int b = blockIdx.x/3, m = blockIdx.x%3, c = threadIdx.x;
  __shared__ __align__(16) float sT[64*68];
  const float* w1 = W + OFF_W1B + ((size_t)b*4+m)*MSZ;
  const __hip_bfloat16* hx = B + BOFF_HX + ((size_t)(b*5+m)*CK)*DD;
  const float* xp = x + ((size_t)b*TT + (size_t)chunk*CK)*DD;
  float acc[64];
  #pragma unroll
  for (int t=0;t<64;t++) acc[t]=0.0f;
  for (int seg=0; seg<4; seg++){
    int i0 = seg*64;
    for (int l=threadIdx.x; l<4096; l+=256){
      int t=l>>6, ii=l&63;
      sT[t*68+ii] = bf(hx[(size_t)t*DD + i0+ii]);
    }
    __syncthreads();
    for (int j=0;j<16;j++){
      float4 wv = *(const float4*)(w1 + (size_t)c*DD + i0 + j*4);
      #pragma unroll
      for (int t=0;t<64;t++){
        float4 hv = *(const float4*)(sT + t*68 + j*4);
        acc[t] += hv.x*wv.x + hv.y*wv.y + hv.z*wv.z + hv.w*wv.w;
      }
    }
    __syncthreads();
  }
  __hip_bfloat16* fd = B + BOFF_F + ((size_t)m*NB + b)*CK*DD;
  #pragma unroll
  for (int t=0;t<64;t++)
    fd[(size_t)t*DD+c] = __float2bfloat16(xp[(size_t)t*DD+c] + acc[t]);
}

// ---------------- k3: row stats (grid NB) ----------------
__global__ __launch_bounds__(256) void k3(const float* __restrict__ x,
        float* __restrict__ W, const __hip_bfloat16* __restrict__ B, int chunk)
{
  int b = blockIdx.x, tid = threadIdx.x, t = tid>>2, q4 = tid&3;
  __shared__ float r5[5][64][4];
  __shared__ float sg[64];
  const float* xp = x + ((size_t)b*TT + (size_t)chunk*CK)*DD;
  const __hip_bfloat16* fk = B + BOFF_F + ((size_t)0*NB+b)*CK*DD;
  const __hip_bfloat16* fv = B + BOFF_F + ((size_t)1*NB+b)*CK*DD;
  const __hip_bfloat16* fq = B + BOFF_F + ((size_t)2*NB+b)*CK*DD;
  const __hip_bfloat16* he = B + BOFF_HX + ((size_t)(b*5+3)*CK)*DD;
  const __hip_bfloat16* ha = B + BOFF_HX + ((size_t)(b*5+4)*CK)*DD;
  const float* w1e = W + OFF_W1S + ((size_t)b*2+0)*DD;
  const float* w1a = W + OFF_W1S + ((size_t)b*2+1)*DD;
  const float* wse = W + OFF_WSK + ((size_t)b*2+0)*DD;
  const float* wsa = W + OFF_WSK + ((size_t)b*2+1)*DD;
  float pk=0,pq=0,pv=0,pe=0,pa=0;
  for (int cc=0; cc<64; cc++){
    int c = q4*64+cc;
    size_t idx = (size_t)t*DD + c;
    float kv = bf(fk[idx]); pk += kv*kv;
    float qv = bf(fq[idx]); pq += qv*qv;
    pv += bf(fv[idx]);
    float xv = xp[idx];
    pe += xv*wse[c] + bf(he[idx])*w1e[c];
    pa += xv*wsa[c] + bf(ha[idx])*w1a[c];
  }
  r5[0][t][q4]=pk; r5[1][t][q4]=pq; r5[2][t][q4]=pv; r5[3][t][q4]=pe; r5[4][t][q4]=pa;
  __syncthreads();
  if (tid < 64){
    float sk = r5[0][tid][0]+r5[0][tid][1]+r5[0][tid][2]+r5[0][tid][3];
    float sq = r5[1][tid][0]+r5[1][tid][1]+r5[1][tid][2]+r5[1][tid][3];
    float sv = r5[2][tid][0]+r5[2][tid][1]+r5[2][tid][2]+r5[2][tid][3];
    float fe = r5[3][tid][0]+r5[3][tid][1]+r5[3][tid][2]+r5[3][tid][3];
    float fa = r5[4][tid][0]+r5[4][tid][1]+r5[4][tid][2]+r5[4][tid][3];
    W[OFF_SCK + (size_t)b*CK+tid] = 1.0f/fmaxf(sqrtf(sk), EPSV);
    W[OFF_SCQ + (size_t)b*CK+tid] = 1.0f/fmaxf(sqrtf(sq), EPSV);
    W[OFF_VSUM+ (size_t)b*CK+tid] = sv;
    float sp = (fe>0.0f) ? (fe + log1pf(expf(-fe))) : log1pf(expf(fe));
    W[OFF_ETA + (size_t)b*CK+tid] = sp*ETA_SC;
    sg[tid] = 1.0f/(1.0f+expf(-fa));
  }
  __syncthreads();
  if (tid == 0){
    float a = 1.0f;
    for (int tt=0;tt<64;tt++) a *= sg[tt];
    W[OFF_ABAR + b] = a;
  }
}

// ---------------- k4: ZU (m 0..5) and ZO (m==6)  (grid NB*7) ----------------
__global__ __launch_bounds__(256) void k4(const float* __restrict__ W,
        __hip_bfloat16* __restrict__ B)
{
  int b = blockIdx.x/7, m = blockIdx.x%7, c = threadIdx.x;
  __shared__ __align__(16) float sT[64*68];
  __shared__ float scl[64];
  const __hip_bfloat16* src = B + BOFF_F + ((size_t)((m==6)?2:0)*NB + b)*CK*DD;
  const float* scp = W + ((m==6)?OFF_SCQ:OFF_SCK) + (size_t)b*CK;
  const float* w2 = W + OFF_W2 + ((size_t)b*6 + ((m==6)?5:m))*MSZ;
  if (threadIdx.x < 64) scl[threadIdx.x] = scp[threadIdx.x];
  float zz[64];
  #pragma unroll
  for (int t=0;t<64;t++) zz[t]=0.0f;
  for (int seg=0; seg<4; seg++){
    int i0 = seg*64;
    for (int l=threadIdx.x; l<4096; l+=256){
      int t=l>>6, ii=l&63;
      sT[t*68+ii] = bf(src[(size_t)t*DD + i0+ii]);
    }
    __syncthreads();
    for (int j=0;j<16;j++){
      float4 wv = *(const float4*)(w2 + (size_t)c*DD + i0 + j*4);
      #pragma unroll
      for (int t=0;t<64;t++){
        float4 xv = *(const float4*)(sT + t*68 + j*4);
        zz[t] += xv.x*wv.x + xv.y*wv.y + xv.z*wv.z + xv.w*wv.w;
      }
    }
    __syncthreads();
  }
  __hip_bfloat16* dst = (m<6) ? (B + BOFF_ZU + ((size_t)(b*6+m)*CK)*DD)
                              : (B + BOFF_ZO + ((size_t)b*CK)*DD);
  #pragma unroll
  for (int t=0;t<64;t++) dst[(size_t)t*DD+c] = __float2bfloat16(zz[t]*scl[t]);
}

// ---------------- k5: g (big), o (fp32 out), g (small)  (grid NB*7) ----------------
__global__ __launch_bounds__(256) void k5(float* __restrict__ W,
        __hip_bfloat16* __restrict__ B, float* __restrict__ out, int chunk)
{
  int b = blockIdx.x/7, r = blockIdx.x%7, c = threadIdx.x;
  __shared__ __align__(16) float sT[64*68];
  __shared__ float scl[64];
  const __hip_bfloat16* fk = B + BOFF_F + ((size_t)0*NB+b)*CK*DD;
  const __hip_bfloat16* fv = B + BOFF_F + ((size_t)1*NB+b)*CK*DD;
  const __hip_bfloat16* fq = B + BOFF_F + ((size_t)2*NB+b)*CK*DD;
  if (r < 5){
    int m  = (r>=3)?5:r;
    int bi = (r>=3)?3:r;
    const __hip_bfloat16* zsrc = (r==4) ? (B + BOFF_ZO + ((size_t)b*CK)*DD)
                                        : (B + BOFF_ZU + ((size_t)(b*6+m)*CK)*DD);
    const float* w1 = W + OFF_W1B + ((size_t)b*4+bi)*MSZ;
    const float* scp = W + ((r==4)?OFF_SCQ:OFF_SCK) + (size_t)b*CK;
    if (threadIdx.x < 64) scl[threadIdx.x] = scp[threadIdx.x];
    float acc[64];
    #pragma unroll
    for (int t=0;t<64;t++) acc[t]=0.0f;
    for (int seg=0; seg<4; seg++){
      int i0 = seg*64;
      for (int l=threadIdx.x; l<4096; l+=256){
        int t=l>>6, ii=l&63;
        sT[t*68+ii] = geluf(bf(zsrc[(size_t)t*DD + i0+ii]));
      }
      __syncthreads();
      for (int j=0;j<16;j++){
        float4 wv = *(const float4*)(w1 + (size_t)c*DD + i0 + j*4);
        #pragma unroll
        for (int t=0;t<64;t++){
          float4 hv = *(const float4*)(sT + t*68 + j*4);
          acc[t] += hv.x*wv.x + hv.y*wv.y + hv.z*wv.z + hv.w*wv.w;
        }
      }
      __syncthreads();
    }
    if (r == 4){
      // *** OUTPUT IS FLOAT32 (reference returns jnp.float32) ***
      float* op = out + ((size_t)b*TT + (size_t)chunk*CK)*DD;
      #pragma unroll
      for (int t=0;t<64;t++)
        op[(size_t)t*DD+c] = bf(fq[(size_t)t*DD+c])*scl[t] + acc[t];
    } else {
      __hip_bfloat16* gd = B + BOFF_GB + ((size_t)(b*4+r)*CK)*DD;
      #pragma unroll
      for (int t=0;t<64;t++){
        float f = bf(fk[(size_t)t*DD+c])*scl[t] + acc[t];
        gd[(size_t)t*DD+c] = __float2bfloat16(2.0f*(f - bf(fv[(size_t)t*DD+c])));
      }
    }
  } else {
    int sm = r-5, m = 3+sm;
    __shared__ float pw[4*64];
    const __hip_bfloat16* zu = B + BOFF_ZU + ((size_t)(b*6+m)*CK)*DD;
    const float* w1s = W + OFF_W1S + ((size_t)b*2+sm)*DD;
    const float* wsk = W + OFF_WSK + ((size_t)b*2+sm)*DD;
    const float* scp = W + OFF_SCK + (size_t)b*CK;
    if (threadIdx.x < 64) scl[threadIdx.x] = scp[threadIdx.x];
    __syncthreads();
    float w1v = w1s[c], wsv = wsk[c];
    float p[64];
    #pragma unroll
    for (int t=0;t<64;t++){
      size_t idx = (size_t)t*DD + c;
      p[t] = bf(fk[idx])*scl[t]*wsv + geluf(bf(zu[idx]))*w1v;
    }
    int lane = threadIdx.x & 63, w = threadIdx.x >> 6;
    #pragma unroll
    for (int t=0;t<64;t++){
      float v = wsum(p[t]);
      if (lane == t) pw[w*64+t] = v;
    }
    __syncthreads();
    if (threadIdx.x < 64){
      int t = threadIdx.x;
      float f = pw[0*64+t]+pw[1*64+t]+pw[2*64+t]+pw[3*64+t];
      float vs = W[OFF_VSUM + (size_t)b*CK + t];
      W[OFF_GS + ((size_t)b*2+sm)*CK + t] = 2.0f*((float)DD*f - vs);
    }
  }
}

// ---------------- k6: P = (g @ w1old) * dgelu(z) * eta  (grid NB*6) ----------------
__global__ __launch_bounds__(256) void k6(const float* __restrict__ W,
        __hip_bfloat16* __restrict__ B)
{
  int b = blockIdx.x/6, m = blockIdx.x%6, c = threadIdx.x;
  __shared__ __align__(16) float sT[64*68];
  __shared__ float et[64];
  if (threadIdx.x < 64) et[threadIdx.x] = W[OFF_ETA + (size_t)b*CK + threadIdx.x];
  float pp[64];
  #pragma unroll
  for (int t=0;t<64;t++) pp[t]=0.0f;
  if (m!=3 && m!=4){
    int bi = bigIdx(m);
    const __hip_bfloat16* gb = B + BOFF_GB + ((size_t)(b*4+bi)*CK)*DD;
    const float* w1 = W + OFF_W1B + ((size_t)b*4+bi)*MSZ;
    for (int seg=0; seg<4; seg++){
      int o0 = seg*64;
      for (int l=threadIdx.x; l<4096; l+=256){
        int t=l>>6, oo=l&63;
        sT[t*68+oo] = bf(gb[(size_t)t*DD + o0+oo]);
      }
      __syncthreads();
      for (int j=0;j<16;j++){
        float wq0 = w1[(size_t)(o0+j*4+0)*DD + c];
        float wq1 = w1[(size_t)(o0+j*4+1)*DD + c];
        float wq2 = w1[(size_t)(o0+j*4+2)*DD + c];
        float wq3 = w1[(size_t)(o0+j*4+3)*DD + c];
        #pragma unroll
        for (int t=0;t<64;t++){
          float4 g4 = *(const float4*)(sT + t*68 + j*4);
          pp[t] += g4.x*wq0 + g4.y*wq1 + g4.z*wq2 + g4.w*wq3;
        }
      }
      __syncthreads();
    }
  } else {
    int sm = m-3;
    const float* w1s = W + OFF_W1S + ((size_t)b*2+sm)*DD;
    float w1v = w1s[c];
    __syncthreads();
    #pragma unroll
    for (int t=0;t<64;t++) pp[t] = W[OFF_GS + ((size_t)b*2+sm)*CK + t] * w1v;
  }
  const __hip_bfloat16* zu = B + BOFF_ZU + ((size_t)(b*6+m)*CK)*DD;
  __hip_bfloat16* pd = B + BOFF_P + ((size_t)(b*6+m)*CK)*DD;
  #pragma unroll
  for (int t=0;t<64;t++){
    size_t idx = (size_t)t*DD + c;
    pd[idx] = __float2bfloat16(pp[t]*dgeluf(bf(zu[idx]))*et[t]);
  }
}

// ---------------- k7: in-place state updates  (grid NB*11) ----------------
__global__ __launch_bounds__(256) void k7(float* __restrict__ W,
        const __hip_bfloat16* __restrict__ B)
{
  int b = blockIdx.x/11, r = blockIdx.x%11, c = threadIdx.x;
  __shared__ __align__(16) float sT[64*68];
  __shared__ float et[64];
  __shared__ float ssk[64];
  float abar = W[OFF_ABAR + b];
  if (threadIdx.x < 64){
    et[threadIdx.x]  = W[OFF_ETA + (size_t)b*CK + threadIdx.x];
    ssk[threadIdx.x] = W[OFF_SCK + (size_t)b*CK + threadIdx.x];
  }
  __syncthreads();
  const __hip_bfloat16* fk = B + BOFF_F + ((size_t)0*NB+b)*CK*DD;
  if (r < 4){
    int m = (r==3)?5:r;
    const __hip_bfloat16* zu = B + BOFF_ZU + ((size_t)(b*6+m)*CK)*DD;
    const __hip_bfloat16* gb = B + BOFF_GB + ((size_t)(b*4+r)*CK)*DD;
    float* w1 = W + OFF_W1B + ((size_t)b*4+r)*MSZ;
    float hv[64];
    #pragma unroll
    for (int t=0;t<64;t++) hv[t] = geluf(bf(zu[(size_t)t*DD+c]));
    for (int seg=0; seg<4; seg++){
      int o0 = seg*64;
      for (int l=threadIdx.x; l<4096; l+=256){
        int t=l>>6, oo=l&63;
        sT[oo*68+t] = bf(gb[(size_t)t*DD + o0+oo]) * et[t];
      }
      __syncthreads();
      for (int oo=0; oo<64; oo++){
        float s = 0.0f;
        #pragma unroll
        for (int t4=0; t4<16; t4++){
          float4 g4 = *(const float4*)(sT + oo*68 + t4*4);
          s += g4.x*hv[4*t4] + g4.y*hv[4*t4+1] + g4.z*hv[4*t4+2] + g4.w*hv[4*t4+3];
        }
        size_t idx = (size_t)(o0+oo)*DD + c;
        w1[idx] = abar*w1[idx] - s;
      }
      __syncthreads();
    }
  } else if (r < 10){
    int m = r-4;
    const __hip_bfloat16* pd = B + BOFF_P + ((size_t)(b*6+m)*CK)*DD;
    float* w2 = W + OFF_W2 + ((size_t)b*6+m)*MSZ;
    float kc[64];
    #pragma unroll
    for (int t=0;t<64;t++) kc[t] = bf(fk[(size_t)t*DD+c]) * ssk[t];
    for (int seg=0; seg<4; seg++){
      int h0 = seg*64;
      for (int l=threadIdx.x; l<4096; l+=256){
        int t=l>>6, hh=l&63;
        sT[hh*68+t] = bf(pd[(size_t)t*DD + h0+hh]);
      }
      __syncthreads();
      for (int hh=0; hh<64; hh++){
        float s = 0.0f;
        #pragma unroll
        for (int t4=0; t4<16; t4++){
          float4 p4 = *(const float4*)(sT + hh*68 + t4*4);
          s += p4.x*kc[4*t4] + p4.y*kc[4*t4+1] + p4.z*kc[4*t4+2] + p4.w*kc[4*t4+3];
        }
        size_t idx = (size_t)(h0+hh)*DD + c;
        w2[idx] = abar*w2[idx] - s;
      }
      __syncthreads();
    }
  } else {
    for (int sm=0; sm<2; sm++){
      int m = 3+sm;
      const __hip_bfloat16* zu = B + BOFF_ZU + ((size_t)(b*6+m)*CK)*DD;
      float s1=0.0f, s2=0.0f;
      #pragma unroll
      for (int t=0;t<64;t++){
        float ge = W[OFF_GS + ((size_t)b*2+sm)*CK + t] * et[t];
        size_t idx = (size_t)t*DD + c;
        s1 += ge * geluf(bf(zu[idx]));
        s2 += ge * bf(fk[idx]) * ssk[t];
      }
      float* w1s = W + OFF_W1S + ((size_t)b*2+sm)*DD;
      float* wsk = W + OFF_WSK + ((size_t)b*2+sm)*DD;
      w1s[c] = abar*w1s[c] - s1;
      wsk[c] = abar*wsk[c] - s2;
    }
  }
}

// ---------------- host ----------------
extern "C" void kernel_launch(void* const* d_in, const int* in_sizes, int n_in,
                              void* d_out, int out_size, void* d_ws, size_t ws_size,
                              hipStream_t stream){
  const float* x = (const float*)d_in[0];
  float* W = (float*)d_ws;
  __hip_bfloat16* B = (__hip_bfloat16*)(W + FTOT);
  float* out = (float*)d_out;   // reference output dtype is float32

  initk<<<NB*6, 256, 0, stream>>>(W,
      (const float*)d_in[1], (const float*)d_in[2],
      (const float*)d_in[3], (const float*)d_in[4],
      (const float*)d_in[5], (const float*)d_in[6],
      (const float*)d_in[7], (const float*)d_in[8],
      (const float*)d_in[9], (const float*)d_in[10],
      (const float*)d_in[11], (const float*)d_in[12],
      (const float*)d_in[13], (const float*)d_in[14]);
  for (int c=0;c<NCK;c++){
    k1<<<NB*5, 256, 0, stream>>>(x, W, B, c);
    k2<<<NB*3, 256, 0, stream>>>(x, W, B, c);
    k3<<<NB,   256, 0, stream>>>(x, W, B, c);
    k4<<<NB*7, 256, 0, stream>>>(W, B);
    k5<<<NB*7, 256, 0, stream>>>(W, B, out, c);
    k6<<<NB*6, 256, 0, stream>>>(W, B);
    k7<<<NB*11,256, 0, stream>>>(W, B);
  }
}

// Round 13
// 21950.514 us; speedup vs baseline: 2.5914x; 2.5914x over previous
//
#include <hip/hip_runtime.h>
#include <hip/hip_bf16.h>
#include <math.h>

// ---------------- problem constants ----------------
constexpr int NB  = 8;
constexpr int TT  = 4096;
constexpr int DD  = 256;
constexpr int CK  = 64;
constexpr int NCK = 64;
constexpr float ETA_SC = 1e-3f;
constexpr float EPSV   = 1e-6f;

constexpr size_t MSZ = (size_t)DD*DD;   // 65536

// ---------- fp32 region (element offsets into float* W) ----------
constexpr size_t OFF_W2  = 0;                               // [8][6][256*256]
constexpr size_t OFF_W1B = OFF_W2  + (size_t)NB*6*MSZ;      // [8][4][256*256]  (k,v,q,mem)
constexpr size_t OFF_W1S = OFF_W1B + (size_t)NB*4*MSZ;      // [8][2][256]
constexpr size_t OFF_WSK = OFF_W1S + (size_t)NB*2*DD;       // [8][2][256]
constexpr size_t OFF_SCK = OFF_WSK + (size_t)NB*2*DD;       // [8][64]
constexpr size_t OFF_SCQ = OFF_SCK + (size_t)NB*CK;         // [8][64]
constexpr size_t OFF_VSUM= OFF_SCQ + (size_t)NB*CK;         // [8][64]
constexpr size_t OFF_ETA = OFF_VSUM+ (size_t)NB*CK;         // [8][64]
constexpr size_t OFF_GS  = OFF_ETA + (size_t)NB*CK;         // [8][2][64]
constexpr size_t OFF_ABAR= OFF_GS  + (size_t)NB*2*CK;       // [8]
constexpr size_t FTOT    = OFF_ABAR + NB;

// ---------- bf16 region (element offsets into __hip_bfloat16* B) ----------
constexpr size_t BOFF_HX = 0;                               // [8][5][64][256]
constexpr size_t BOFF_F  = BOFF_HX + (size_t)NB*5*CK*DD;    // [3][8][64][256]
constexpr size_t BOFF_ZU = BOFF_F  + (size_t)3*NB*CK*DD;    // [8][6][64][256]
constexpr size_t BOFF_ZO = BOFF_ZU + (size_t)NB*6*CK*DD;    // [8][64][256]
constexpr size_t BOFF_GB = BOFF_ZO + (size_t)NB*CK*DD;      // [8][4][64][256]
constexpr size_t BOFF_P  = BOFF_GB + (size_t)NB*4*CK*DD;    // [8][6][64][256]

__device__ __forceinline__ int bigIdx(int m){ return (m==5)?3:m; }

__device__ __forceinline__ float geluf(float z){
  return 0.5f*z*(1.0f + erff(z*0.70710678118654752440f));
}
__device__ __forceinline__ float dgeluf(float z){
  float cdf = 0.5f*(1.0f + erff(z*0.70710678118654752440f));
  float pdf = expf(-0.5f*z*z)*0.39894228040143267794f;
  return cdf + z*pdf;
}
__device__ __forceinline__ float bf(__hip_bfloat16 v){ return __bfloat162float(v); }
__device__ __forceinline__ float wsum(float v){
  #pragma unroll
  for (int off=32; off>0; off>>=1) v += __shfl_xor(v, off, 64);
  return v;
}

// seg-GEMM core: 16-row A tile (LDS, padded stride 68) x W^T (row-major 256x256)
// thread (cg=tid&63, rg=tid>>6): rows rg*4+rr (local), cols cg+64*j. 16 FMA per A-read.
__device__ __forceinline__ void gseg(const float* __restrict__ sA,
      const float* __restrict__ Wm, int i0, int cg, int rg, float acc[4][4]){
  for (int kk=0; kk<64; kk+=4){
    float4 w0 = *(const float4*)(Wm + (size_t)(cg      )*DD + i0+kk);
    float4 w1 = *(const float4*)(Wm + (size_t)(cg +  64)*DD + i0+kk);
    float4 w2 = *(const float4*)(Wm + (size_t)(cg + 128)*DD + i0+kk);
    float4 w3 = *(const float4*)(Wm + (size_t)(cg + 192)*DD + i0+kk);
    #pragma unroll
    for (int rr=0; rr<4; rr++){
      float4 a = *(const float4*)(sA + (rg*4+rr)*68 + kk);
      acc[rr][0] += a.x*w0.x + a.y*w0.y + a.z*w0.z + a.w*w0.w;
      acc[rr][1] += a.x*w1.x + a.y*w1.y + a.z*w1.z + a.w*w1.w;
      acc[rr][2] += a.x*w2.x + a.y*w2.y + a.z*w2.z + a.w*w2.w;
      acc[rr][3] += a.x*w3.x + a.y*w3.y + a.z*w3.z + a.w*w3.w;
    }
  }
}

// ---------------- init ----------------
__global__ __launch_bounds__(256) void initk(float* __restrict__ W,
  const float* kw1, const float* kw2, const float* vw1, const float* vw2,
  const float* qw1, const float* qw2, const float* ew1, const float* ew2,
  const float* ewsk, const float* aw1, const float* aw2, const float* awsk,
  const float* mw1, const float* mw2)
{
  int b = blockIdx.x/6, m = blockIdx.x%6;
  const float *w1s=nullptr,*w2s=nullptr,*wsks=nullptr;
  switch(m){
    case 0: w1s=kw1; w2s=kw2; break;
    case 1: w1s=vw1; w2s=vw2; break;
    case 2: w1s=qw1; w2s=qw2; break;
    case 3: w1s=ew1; w2s=ew2; wsks=ewsk; break;
    case 4: w1s=aw1; w2s=aw2; wsks=awsk; break;
    default: w1s=mw1; w2s=mw2; break;
  }
  float* w2d = W + OFF_W2 + ((size_t)b*6+m)*MSZ;
  for (size_t i=threadIdx.x; i<MSZ; i+=256) w2d[i] = w2s[i];
  if (m==3 || m==4){
    int sm = m-3;
    float* w1d = W + OFF_W1S + ((size_t)b*2+sm)*DD;
    float* wsd = W + OFF_WSK + ((size_t)b*2+sm)*DD;
    for (int i=threadIdx.x;i<DD;i+=256){ w1d[i]=w1s[i]; wsd[i]=wsks[i]; }
  } else {
    float* w1d = W + OFF_W1B + ((size_t)b*4+bigIdx(m))*MSZ;
    for (size_t i=threadIdx.x;i<MSZ;i+=256) w1d[i] = w1s[i];
  }
}

// ---------------- k1: Hx = gelu(x @ w2^T), mems 0..4, 4 row-blocks (grid NB*20) ----------------
__global__ __launch_bounds__(256) void k1(const float* __restrict__ x,
        const float* __restrict__ W, __hip_bfloat16* __restrict__ B, int chunk)
{
  int blk = blockIdx.x, b = blk/20, rem = blk%20, m = rem>>2, t0 = (rem&3)*16;
  int tid = threadIdx.x, cg = tid&63, rg = tid>>6;
  __shared__ __align__(16) float sA[16*68];
  const float* w2 = W + OFF_W2 + ((size_t)b*6+m)*MSZ;
  const float* xp = x + ((size_t)b*TT + (size_t)chunk*CK)*DD;
  float acc[4][4];
  #pragma unroll
  for (int i=0;i<4;i++)
    #pragma unroll
    for (int j=0;j<4;j++) acc[i][j]=0.0f;
  for (int seg=0; seg<4; seg++){
    int i0 = seg*64;
    for (int l=tid; l<1024; l+=256){
      int tl=l>>6, ii=l&63;
      sA[tl*68+ii] = xp[(size_t)(t0+tl)*DD + i0+ii];
    }
    __syncthreads();
    gseg(sA, w2, i0, cg, rg, acc);
    __syncthreads();
  }
  __hip_bfloat16* hx = B + BOFF_HX + ((size_t)(b*5+m)*CK)*DD;
  #pragma unroll
  for (int rr=0;rr<4;rr++)
    #pragma unroll
    for (int j=0;j<4;j++)
      hx[(size_t)(t0+rg*4+rr)*DD + cg+64*j] = __float2bfloat16(geluf(acc[rr][j]));
}

// ---------------- k2: F = x + Hx @ w1^T, mems 0..2 (grid NB*12) ----------------
__global__ __launch_bounds__(256) void k2(const float* __restrict__ x,
        const float* __restrict__ W, __hip_bfloat16* __restrict__ B, int chunk)
{
  int blk = blockIdx.x, b = blk/12, rem = blk%12, m = rem>>2, t0 = (rem&3)*16;
  int tid = threadIdx.x, cg = tid&63, rg = tid>>6;
  __shared__ __align__(16) float sA[16*68];
  const float* w1 = W + OFF_W1B + ((size_t)b*4+m)*MSZ;
  const __hip_bfloat16* hx = B + BOFF_HX + ((size_t)(b*5+m)*CK)*DD;
  const float* xp = x + ((size_t)b*TT + (size_t)chunk*CK)*DD;
  float acc[4][4];
  #pragma unroll
  for (int i=0;i<4;i++)
    #pragma unroll
    for (int j=0;j<4;j++) acc[i][j]=0.0f;
  for (int seg=0; seg<4; seg++){
    int i0 = seg*64;
    for (int l=tid; l<1024; l+=256){
      int tl=l>>6, ii=l&63;
      sA[tl*68+ii] = bf(hx[(size_t)(t0+tl)*DD + i0+ii]);
    }
    __syncthreads();
    gseg(sA, w1, i0, cg, rg, acc);
    __syncthreads();
  }
  __hip_bfloat16* fd = B + BOFF_F + ((size_t)m*NB + b)*CK*DD;
  #pragma unroll
  for (int rr=0;rr<4;rr++)
    #pragma unroll
    for (int j=0;j<4;j++){
      size_t idx = (size_t)(t0+rg*4+rr)*DD + cg+64*j;
      fd[idx] = __float2bfloat16(xp[idx] + acc[rr][j]);
    }
}

// ---------------- k3: row stats (grid NB) ----------------
__global__ __launch_bounds__(256) void k3(const float* __restrict__ x,
        float* __restrict__ W, const __hip_bfloat16* __restrict__ B, int chunk)
{
  int b = blockIdx.x, tid = threadIdx.x, t = tid>>2, q4 = tid&3;
  __shared__ float r5[5][64][4];
  __shared__ float sg[64];
  const float* xp = x + ((size_t)b*TT + (size_t)chunk*CK)*DD;
  const __hip_bfloat16* fk = B + BOFF_F + ((size_t)0*NB+b)*CK*DD;
  const __hip_bfloat16* fv = B + BOFF_F + ((size_t)1*NB+b)*CK*DD;
  const __hip_bfloat16* fq = B + BOFF_F + ((size_t)2*NB+b)*CK*DD;
  const __hip_bfloat16* he = B + BOFF_HX + ((size_t)(b*5+3)*CK)*DD;
  const __hip_bfloat16* ha = B + BOFF_HX + ((size_t)(b*5+4)*CK)*DD;
  const float* w1e = W + OFF_W1S + ((size_t)b*2+0)*DD;
  const float* w1a = W + OFF_W1S + ((size_t)b*2+1)*DD;
  const float* wse = W + OFF_WSK + ((size_t)b*2+0)*DD;
  const float* wsa = W + OFF_WSK + ((size_t)b*2+1)*DD;
  float pk=0,pq=0,pv=0,pe=0,pa=0;
  for (int cc=0; cc<64; cc++){
    int c = q4*64+cc;
    size_t idx = (size_t)t*DD + c;
    float kv = bf(fk[idx]); pk += kv*kv;
    float qv = bf(fq[idx]); pq += qv*qv;
    pv += bf(fv[idx]);
    float xv = xp[idx];
    pe += xv*wse[c] + bf(he[idx])*w1e[c];
    pa += xv*wsa[c] + bf(ha[idx])*w1a[c];
  }
  r5[0][t][q4]=pk; r5[1][t][q4]=pq; r5[2][t][q4]=pv; r5[3][t][q4]=pe; r5[4][t][q4]=pa;
  __syncthreads();
  if (tid < 64){
    float sk = r5[0][tid][0]+r5[0][tid][1]+r5[0][tid][2]+r5[0][tid][3];
    float sq = r5[1][tid][0]+r5[1][tid][1]+r5[1][tid][2]+r5[1][tid][3];
    float sv = r5[2][tid][0]+r5[2][tid][1]+r5[2][tid][2]+r5[2][tid][3];
    float fe = r5[3][tid][0]+r5[3][tid][1]+r5[3][tid][2]+r5[3][tid][3];
    float fa = r5[4][tid][0]+r5[4][tid][1]+r5[4][tid][2]+r5[4][tid][3];
    W[OFF_SCK + (size_t)b*CK+tid] = 1.0f/fmaxf(sqrtf(sk), EPSV);
    W[OFF_SCQ + (size_t)b*CK+tid] = 1.0f/fmaxf(sqrtf(sq), EPSV);
    W[OFF_VSUM+ (size_t)b*CK+tid] = sv;
    float sp = (fe>0.0f) ? (fe + log1pf(expf(-fe))) : log1pf(expf(fe));
    W[OFF_ETA + (size_t)b*CK+tid] = sp*ETA_SC;
    sg[tid] = 1.0f/(1.0f+expf(-fa));
  }
  __syncthreads();
  if (tid == 0){
    float a = 1.0f;
    for (int tt=0;tt<64;tt++) a *= sg[tt];
    W[OFF_ABAR + b] = a;
  }
}

// ---------------- k4: ZU (m 0..5) / ZO (m==6), 4 row-blocks (grid NB*28) ----------------
__global__ __launch_bounds__(256) void k4(const float* __restrict__ W,
        __hip_bfloat16* __restrict__ B)
{
  int blk = blockIdx.x, b = blk/28, rem = blk%28, m = rem>>2, t0 = (rem&3)*16;
  int tid = threadIdx.x, cg = tid&63, rg = tid>>6;
  __shared__ __align__(16) float sA[16*68];
  const __hip_bfloat16* src = B + BOFF_F + ((size_t)((m==6)?2:0)*NB + b)*CK*DD;
  const float* w2 = W + OFF_W2 + ((size_t)b*6 + ((m==6)?5:m))*MSZ;
  size_t sclb = ((m==6)?OFF_SCQ:OFF_SCK) + (size_t)b*CK;
  float acc[4][4];
  #pragma unroll
  for (int i=0;i<4;i++)
    #pragma unroll
    for (int j=0;j<4;j++) acc[i][j]=0.0f;
  for (int seg=0; seg<4; seg++){
    int i0 = seg*64;
    for (int l=tid; l<1024; l+=256){
      int tl=l>>6, ii=l&63;
      sA[tl*68+ii] = bf(src[(size_t)(t0+tl)*DD + i0+ii]);
    }
    __syncthreads();
    gseg(sA, w2, i0, cg, rg, acc);
    __syncthreads();
  }
  __hip_bfloat16* dst = (m<6) ? (B + BOFF_ZU + ((size_t)(b*6+m)*CK)*DD)
                              : (B + BOFF_ZO + ((size_t)b*CK)*DD);
  #pragma unroll
  for (int rr=0;rr<4;rr++){
    float sclv = W[sclb + t0+rg*4+rr];
    #pragma unroll
    for (int j=0;j<4;j++)
      dst[(size_t)(t0+rg*4+rr)*DD + cg+64*j] = __float2bfloat16(acc[rr][j]*sclv);
  }
}

// ---------------- k5: g big / o (4 row-blocks) + g small (grid NB*22) ----------------
__global__ __launch_bounds__(256) void k5(float* __restrict__ W,
        __hip_bfloat16* __restrict__ B, float* __restrict__ out, int chunk)
{
  int blk = blockIdx.x, b = blk/22, rem = blk%22;
  int tid = threadIdx.x;
  __shared__ __align__(16) float sA[16*68];
  __shared__ float pw[4*64];
  __shared__ float scl[64];
  const __hip_bfloat16* fk = B + BOFF_F + ((size_t)0*NB+b)*CK*DD;
  const __hip_bfloat16* fv = B + BOFF_F + ((size_t)1*NB+b)*CK*DD;
  const __hip_bfloat16* fq = B + BOFF_F + ((size_t)2*NB+b)*CK*DD;
  if (rem < 20){
    int r = rem>>2, t0 = (rem&3)*16;
    int cg = tid&63, rg = tid>>6;
    int m  = (r>=3)?5:r;
    int bi = (r>=3)?3:r;
    const __hip_bfloat16* zsrc = (r==4) ? (B + BOFF_ZO + ((size_t)b*CK)*DD)
                                        : (B + BOFF_ZU + ((size_t)(b*6+m)*CK)*DD);
    const float* w1 = W + OFF_W1B + ((size_t)b*4+bi)*MSZ;
    size_t sclb = ((r==4)?OFF_SCQ:OFF_SCK) + (size_t)b*CK;
    float acc[4][4];
    #pragma unroll
    for (int i=0;i<4;i++)
      #pragma unroll
      for (int j=0;j<4;j++) acc[i][j]=0.0f;
    for (int seg=0; seg<4; seg++){
      int i0 = seg*64;
      for (int l=tid; l<1024; l+=256){
        int tl=l>>6, ii=l&63;
        sA[tl*68+ii] = geluf(bf(zsrc[(size_t)(t0+tl)*DD + i0+ii]));
      }
      __syncthreads();
      gseg(sA, w1, i0, cg, rg, acc);
      __syncthreads();
    }
    if (r == 4){
      float* op = out + ((size_t)b*TT + (size_t)chunk*CK)*DD;
      #pragma unroll
      for (int rr=0;rr<4;rr++){
        int t = t0+rg*4+rr;
        float sclv = W[sclb + t];
        #pragma unroll
        for (int j=0;j<4;j++){
          size_t idx = (size_t)t*DD + cg+64*j;
          op[idx] = bf(fq[idx])*sclv + acc[rr][j];
        }
      }
    } else {
      __hip_bfloat16* gd = B + BOFF_GB + ((size_t)(b*4+r)*CK)*DD;
      #pragma unroll
      for (int rr=0;rr<4;rr++){
        int t = t0+rg*4+rr;
        float sclv = W[sclb + t];
        #pragma unroll
        for (int j=0;j<4;j++){
          size_t idx = (size_t)t*DD + cg+64*j;
          float f = bf(fk[idx])*sclv + acc[rr][j];
          gd[idx] = __float2bfloat16(2.0f*(f - bf(fv[idx])));
        }
      }
    }
  } else {
    int sm = rem-20, m = 3+sm, c = tid;
    const __hip_bfloat16* zu = B + BOFF_ZU + ((size_t)(b*6+m)*CK)*DD;
    const float* w1s = W + OFF_W1S + ((size_t)b*2+sm)*DD;
    const float* wsk = W + OFF_WSK + ((size_t)b*2+sm)*DD;
    const float* scp = W + OFF_SCK + (size_t)b*CK;
    if (tid < 64) scl[tid] = scp[tid];
    __syncthreads();
    float w1v = w1s[c], wsv = wsk[c];
    float p[64];
    #pragma unroll
    for (int t=0;t<64;t++){
      size_t idx = (size_t)t*DD + c;
      p[t] = bf(fk[idx])*scl[t]*wsv + geluf(bf(zu[idx]))*w1v;
    }
    int lane = tid & 63, w = tid >> 6;
    #pragma unroll
    for (int t=0;t<64;t++){
      float v = wsum(p[t]);
      if (lane == t) pw[w*64+t] = v;
    }
    __syncthreads();
    if (tid < 64){
      int t = tid;
      float f = pw[0*64+t]+pw[1*64+t]+pw[2*64+t]+pw[3*64+t];
      float vs = W[OFF_VSUM + (size_t)b*CK + t];
      W[OFF_GS + ((size_t)b*2+sm)*CK + t] = 2.0f*((float)DD*f - vs);
    }
  }
}

// ---------------- k6: P = (g @ w1old)*dgelu*eta, 4 row-blocks + small (grid NB*17) ----------------
__global__ __launch_bounds__(256) void k6(const float* __restrict__ W,
        __hip_bfloat16* __restrict__ B)
{
  int blk = blockIdx.x, b = blk/17, rem = blk%17;
  int tid = threadIdx.x;
  __shared__ __align__(16) float sA[16*68];
  if (rem < 16){
    int mi = rem>>2, t0 = (rem&3)*16;
    int m = (mi==3)?5:mi;
    int cg = tid&63, rg = tid>>6;
    const __hip_bfloat16* gb = B + BOFF_GB + ((size_t)(b*4+mi)*CK)*DD;
    const float* w1 = W + OFF_W1B + ((size_t)b*4+mi)*MSZ;
    float acc[4][4];
    #pragma unroll
    for (int i=0;i<4;i++)
      #pragma unroll
      for (int j=0;j<4;j++) acc[i][j]=0.0f;
    for (int seg=0; seg<4; seg++){
      int o0 = seg*64;
      for (int l=tid; l<1024; l+=256){
        int tl=l>>6, oo=l&63;
        sA[tl*68+oo] = bf(gb[(size_t)(t0+tl)*DD + o0+oo]);
      }
      __syncthreads();
      for (int kk=0; kk<64; kk+=4){
        float wv[4][4];
        #pragma unroll
        for (int s=0;s<4;s++)
          #pragma unroll
          for (int j=0;j<4;j++)
            wv[s][j] = w1[(size_t)(o0+kk+s)*DD + cg+64*j];
        #pragma unroll
        for (int rr=0;rr<4;rr++){
          float4 a = *(const float4*)(sA + (rg*4+rr)*68 + kk);
          #pragma unroll
          for (int j=0;j<4;j++)
            acc[rr][j] += a.x*wv[0][j] + a.y*wv[1][j] + a.z*wv[2][j] + a.w*wv[3][j];
        }
      }
      __syncthreads();
    }
    const __hip_bfloat16* zu = B + BOFF_ZU + ((size_t)(b*6+m)*CK)*DD;
    __hip_bfloat16* pd = B + BOFF_P + ((size_t)(b*6+m)*CK)*DD;
    #pragma unroll
    for (int rr=0;rr<4;rr++){
      int t = t0+rg*4+rr;
      float et = W[OFF_ETA + (size_t)b*CK + t];
      #pragma unroll
      for (int j=0;j<4;j++){
        size_t idx = (size_t)t*DD + cg+64*j;
        pd[idx] = __float2bfloat16(acc[rr][j]*dgeluf(bf(zu[idx]))*et);
      }
    }
  } else {
    int c = tid;
    for (int sm=0; sm<2; sm++){
      int m = 3+sm;
      const __hip_bfloat16* zu = B + BOFF_ZU + ((size_t)(b*6+m)*CK)*DD;
      __hip_bfloat16* pd = B + BOFF_P + ((size_t)(b*6+m)*CK)*DD;
      float w1v = W[OFF_W1S + ((size_t)b*2+sm)*DD + c];
      for (int t=0;t<64;t++){
        float pp = W[OFF_GS + ((size_t)b*2+sm)*CK + t] * w1v;
        float et = W[OFF_ETA + (size_t)b*CK + t];
        size_t idx = (size_t)t*DD + c;
        pd[idx] = __float2bfloat16(pp*dgeluf(bf(zu[idx]))*et);
      }
    }
  }
}

// ---------------- k7: state updates, seg-split (grid NB*41) ----------------
__global__ __launch_bounds__(256) void k7(float* __restrict__ W,
        const __hip_bfloat16* __restrict__ B)
{
  int blk = blockIdx.x, b = blk/41, r = blk%41, c = threadIdx.x;
  __shared__ __align__(16) float sT[64*68];
  __shared__ float et[64];
  __shared__ float ssk[64];
  float abar = W[OFF_ABAR + b];
  if (threadIdx.x < 64){
    et[threadIdx.x]  = W[OFF_ETA + (size_t)b*CK + threadIdx.x];
    ssk[threadIdx.x] = W[OFF_SCK + (size_t)b*CK + threadIdx.x];
  }
  __syncthreads();
  const __hip_bfloat16* fk = B + BOFF_F + ((size_t)0*NB+b)*CK*DD;
  if (r < 16){
    // w1 update, one 64-row seg: mi in {0..3} -> mems {0,1,2,5}
    int mi = r>>2, o0 = (r&3)*64;
    int m = (mi==3)?5:mi;
    const __hip_bfloat16* zu = B + BOFF_ZU + ((size_t)(b*6+m)*CK)*DD;
    const __hip_bfloat16* gb = B + BOFF_GB + ((size_t)(b*4+mi)*CK)*DD;
    float* w1 = W + OFF_W1B + ((size_t)b*4+mi)*MSZ;
    float hv[64];
    #pragma unroll
    for (int t=0;t<64;t++) hv[t] = geluf(bf(zu[(size_t)t*DD+c]));
    for (int l=threadIdx.x; l<4096; l+=256){
      int t=l>>6, oo=l&63;
      sT[oo*68+t] = bf(gb[(size_t)t*DD + o0+oo]) * et[t];
    }
    __syncthreads();
    for (int oo=0; oo<64; oo++){
      float s = 0.0f;
      #pragma unroll
      for (int t4=0; t4<16; t4++){
        float4 g4 = *(const float4*)(sT + oo*68 + t4*4);
        s += g4.x*hv[4*t4] + g4.y*hv[4*t4+1] + g4.z*hv[4*t4+2] + g4.w*hv[4*t4+3];
      }
      size_t idx = (size_t)(o0+oo)*DD + c;
      w1[idx] = abar*w1[idx] - s;
    }
  } else if (r < 40){
    // w2 update, one 64-row seg: m = 0..5
    int m = (r-16)>>2, h0 = ((r-16)&3)*64;
    const __hip_bfloat16* pd = B + BOFF_P + ((size_t)(b*6+m)*CK)*DD;
    float* w2 = W + OFF_W2 + ((size_t)b*6+m)*MSZ;
    float kc[64];
    #pragma unroll
    for (int t=0;t<64;t++) kc[t] = bf(fk[(size_t)t*DD+c]) * ssk[t];
    for (int l=threadIdx.x; l<4096; l+=256){
      int t=l>>6, hh=l&63;
      sT[hh*68+t] = bf(pd[(size_t)t*DD + h0+hh]);
    }
    __syncthreads();
    for (int hh=0; hh<64; hh++){
      float s = 0.0f;
      #pragma unroll
      for (int t4=0; t4<16; t4++){
        float4 p4 = *(const float4*)(sT + hh*68 + t4*4);
        s += p4.x*kc[4*t4] + p4.y*kc[4*t4+1] + p4.z*kc[4*t4+2] + p4.w*kc[4*t4+3];
      }
      size_t idx = (size_t)(h0+hh)*DD + c;
      w2[idx] = abar*w2[idx] - s;
    }
  } else {
    for (int sm=0; sm<2; sm++){
      int m = 3+sm;
      const __hip_bfloat16* zu = B + BOFF_ZU + ((size_t)(b*6+m)*CK)*DD;
      float s1=0.0f, s2=0.0f;
      #pragma unroll
      for (int t=0;t<64;t++){
        float ge = W[OFF_GS + ((size_t)b*2+sm)*CK + t] * et[t];
        size_t idx = (size_t)t*DD + c;
        s1 += ge * geluf(bf(zu[idx]));
        s2 += ge * bf(fk[idx]) * ssk[t];
      }
      float* w1s = W + OFF_W1S + ((size_t)b*2+sm)*DD;
      float* wsk = W + OFF_WSK + ((size_t)b*2+sm)*DD;
      w1s[c] = abar*w1s[c] - s1;
      wsk[c] = abar*wsk[c] - s2;
    }
  }
}

// ---------------- host ----------------
extern "C" void kernel_launch(void* const* d_in, const int* in_sizes, int n_in,
                              void* d_out, int out_size, void* d_ws, size_t ws_size,
                              hipStream_t stream){
  const float* x = (const float*)d_in[0];
  float* W = (float*)d_ws;
  __hip_bfloat16* B = (__hip_bfloat16*)(W + FTOT);
  float* out = (float*)d_out;

  initk<<<NB*6, 256, 0, stream>>>(W,
      (const float*)d_in[1], (const float*)d_in[2],
      (const float*)d_in[3], (const float*)d_in[4],
      (const float*)d_in[5], (const float*)d_in[6],
      (const float*)d_in[7], (const float*)d_in[8],
      (const float*)d_in[9], (const float*)d_in[10],
      (const float*)d_in[11], (const float*)d_in[12],
      (const float*)d_in[13], (const float*)d_in[14]);
  for (int c=0;c<NCK;c++){
    k1<<<NB*20, 256, 0, stream>>>(x, W, B, c);
    k2<<<NB*12, 256, 0, stream>>>(x, W, B, c);
    k3<<<NB,    256, 0, stream>>>(x, W, B, c);
    k4<<<NB*28, 256, 0, stream>>>(W, B);
    k5<<<NB*22, 256, 0, stream>>>(W, B, out, c);
    k6<<<NB*17, 256, 0, stream>>>(W, B);
    k7<<<NB*41, 256, 0, stream>>>(W, B);
  }
}